// Round 1
// baseline (845.672 us; speedup 1.0000x reference)
//
#include <hip/hip_runtime.h>
#include <hip/hip_bf16.h>

typedef __hip_bfloat16 bf16;

// Problem constants
#define BB    4
#define LQ    4096
#define LIN   16464
#define DM    768
#define NH    12
#define HD    64
#define K_DIM 768
// Levels: (112,112),(56,56),(28,28); starts 0,12544,15680; query grid 64x64

typedef __attribute__((ext_vector_type(8))) __bf16 bfrag;
typedef __attribute__((ext_vector_type(4))) float  ffrag;

// ---------------------------------------------------------------------------
// async global->LDS 16B per lane (LDS dest is wave-uniform base + lane*16)
// ---------------------------------------------------------------------------
__device__ __forceinline__ void g2l16(const void* g, void* l) {
    __builtin_amdgcn_global_load_lds(
        (const __attribute__((address_space(1))) void*)g,
        (__attribute__((address_space(3))) void*)l, 16, 0, 0);
}

// ---------------------------------------------------------------------------
// LayerNorm over last dim 768: one wave per row, 4 rows/block.
// Pure shfl_xor reduction — no LDS, no barrier.
// ---------------------------------------------------------------------------
__global__ __launch_bounds__(256) void ln_kernel(
    const float* __restrict__ x, const float* __restrict__ g,
    const float* __restrict__ beta, bf16* __restrict__ y)
{
    int r = blockIdx.x * 4 + (threadIdx.x >> 6);
    int lane = threadIdx.x & 63;
    const float4* xr = (const float4*)(x + (size_t)r * DM);
    float4 v[3];
    #pragma unroll
    for (int i = 0; i < 3; i++) v[i] = xr[lane + 64 * i];
    float s = 0.f, ss = 0.f;
    #pragma unroll
    for (int i = 0; i < 3; i++) {
        s  += v[i].x + v[i].y + v[i].z + v[i].w;
        ss += v[i].x * v[i].x + v[i].y * v[i].y + v[i].z * v[i].z + v[i].w * v[i].w;
    }
    #pragma unroll
    for (int m = 1; m <= 32; m <<= 1) {
        s  += __shfl_xor(s, m);
        ss += __shfl_xor(ss, m);
    }
    float mean = s * (1.f / DM);
    float inv  = rsqrtf(ss * (1.f / DM) - mean * mean + 1e-6f);
    bf16* yr = y + (size_t)r * DM;
    #pragma unroll
    for (int i = 0; i < 3; i++) {
        float4 gg = ((const float4*)g)[lane + 64 * i];
        float4 bb = ((const float4*)beta)[lane + 64 * i];
        union { bf16 h[4]; uint2 u; } p;
        p.h[0] = __float2bfloat16((v[i].x - mean) * inv * gg.x + bb.x);
        p.h[1] = __float2bfloat16((v[i].y - mean) * inv * gg.y + bb.y);
        p.h[2] = __float2bfloat16((v[i].z - mean) * inv * gg.z + bb.z);
        p.h[3] = __float2bfloat16((v[i].w - mean) * inv * gg.w + bb.w);
        *(uint2*)(yr + (lane + 64 * i) * 4) = p.u;
    }
}

// ---------------------------------------------------------------------------
// Cast + transpose weights: W (768 x N f32, row-major) -> Wt (gridX*32 x 768 bf16)
// rows n >= N zero-filled. Grid: (rows/32, 768/32), block 256.
// ---------------------------------------------------------------------------
__global__ __launch_bounds__(256) void cast_transpose(
    const float* __restrict__ W, bf16* __restrict__ Wt, int N)
{
    __shared__ float t[32][33];
    int n0 = blockIdx.x * 32, k0 = blockIdx.y * 32;
    int tx = threadIdx.x & 31, ty = threadIdx.x >> 5;  // ty 0..7
    #pragma unroll
    for (int i = 0; i < 4; i++) {
        int k = k0 + ty + i * 8;
        int n = n0 + tx;
        t[ty + i * 8][tx] = (n < N) ? W[(size_t)k * N + n] : 0.f;
    }
    __syncthreads();
    #pragma unroll
    for (int i = 0; i < 4; i++) {
        int n = n0 + ty + i * 8;
        Wt[(size_t)n * K_DIM + k0 + tx] = __float2bfloat16(t[tx][ty + i * 8]);
    }
}

// ---------------------------------------------------------------------------
// MFMA bf16 GEMM: C(M,N) = A(M,768) @ Wt(N,768)^T + bias
// 128x128 tile, 256 threads (4 waves, 2x2 of 64x64).
// K-step 64 (two BK=32 sub-tiles), DOUBLE-BUFFERED: next K-step's
// global_load_lds issue BEFORE compute of current buffer, so the
// __syncthreads() vmcnt-drain lands after ~600 cy of ds_read+MFMA cover.
// XCD-bijective block swizzle (m204) for A-panel L2 reuse.
// mode 0: bf16 store; mode 2: f32 = resid + gamma*(acc+bias);
// mode 3: f32 store, dual bias split at nsplit; else f32 store.
// ---------------------------------------------------------------------------
__global__ __launch_bounds__(256) void mfma_gemm(
    const bf16*  __restrict__ A,
    const bf16*  __restrict__ Bt,
    const float* __restrict__ bias,
    void*        __restrict__ C,
    const float* __restrict__ resid,
    const float* __restrict__ gamma,
    const float* __restrict__ bias2,
    int M, int N, int mode, int nsplit)
{
    __shared__ __align__(16) char lds[65536];   // 2 buffers x (2 sub-tiles x (A 8K + B 8K))

    int tid  = threadIdx.x;
    int lane = tid & 63;

    // XCD-bijective swizzle: dispatch i lands on XCD i%8; give each XCD a
    // contiguous run of tile ids so neighbor tiles share A-panels in its L2.
    int nwg  = gridDim.x * gridDim.y;
    int orig = blockIdx.y * gridDim.x + blockIdx.x;
    int xcd = orig & 7, within = orig >> 3;
    int q = nwg >> 3, r = nwg & 7;
    int wg = (xcd < r ? xcd * (q + 1) : r * (q + 1) + (xcd - r) * q) + within;
    int bn = (wg % gridDim.x) * 128;
    int bm = (wg / gridDim.x) * 128;

    int wave = tid >> 6;
    int wr = (wave & 1) * 64, wc = (wave >> 1) * 64;

    ffrag acc[4][4] = {};

    // staging (per sub-tile, R3 layout): 512 chunks of 16B; thread covers
    // chunks tid, tid+256. chunk c: row = c>>2, K-octet = (c&3)*8.
    int c0 = tid, c1 = tid + 256;
    int r0 = c0 >> 2, kb0 = (c0 & 3) * 8;
    int r1 = c1 >> 2, kb1 = (c1 & 3) * 8;
    int ra0 = min(bm + r0, M - 1), ra1 = min(bm + r1, M - 1);
    const bf16* gA0 = A  + (size_t)ra0 * K_DIM + kb0;
    const bf16* gA1 = A  + (size_t)ra1 * K_DIM + kb1;
    const bf16* gB0 = Bt + (size_t)(bn + r0) * K_DIM + kb0;
    const bf16* gB1 = Bt + (size_t)(bn + r1) * K_DIM + kb1;

    int mrow = lane & 15;
    int kq   = (lane >> 4) * 8;

    auto stage = [&](char* buf, int k0) {
        #pragma unroll
        for (int s = 0; s < 2; s++) {
            char* As = buf + s * 16384;
            char* Bs = As + 8192;
            int ko = k0 + s * 32;
            g2l16(gA0 + ko, As + c0 * 16);
            g2l16(gA1 + ko, As + c1 * 16);
            g2l16(gB0 + ko, Bs + c0 * 16);
            g2l16(gB1 + ko, Bs + c1 * 16);
        }
    };

    // prologue: fill buffer 0
    stage(lds, 0);
    __syncthreads();

    for (int k0 = 0; k0 < K_DIM; k0 += 64) {
        char* cur = lds + (((k0 >> 6) & 1) ? 32768 : 0);
        char* nxt = lds + (((k0 >> 6) & 1) ? 0 : 32768);
        if (k0 + 64 < K_DIM) stage(nxt, k0 + 64);   // issue-early: flies under MFMA
        #pragma unroll
        for (int s = 0; s < 2; s++) {
            char* As = cur + s * 16384;
            char* Bs = As + 8192;
            bfrag a[4], b[4];
            #pragma unroll
            for (int t = 0; t < 4; t++) {
                a[t] = *(const bfrag*)(As + ((wr + t * 16 + mrow) * 32 + kq) * 2);
                b[t] = *(const bfrag*)(Bs + ((wc + t * 16 + mrow) * 32 + kq) * 2);
            }
            #pragma unroll
            for (int i = 0; i < 4; i++)
                #pragma unroll
                for (int j = 0; j < 4; j++)
                    acc[i][j] = __builtin_amdgcn_mfma_f32_16x16x32_bf16(
                        a[i], b[j], acc[i][j], 0, 0, 0);
        }
        __syncthreads();   // drains vmcnt -> nxt fully written; cur free to overwrite
    }

    // epilogue: C/D layout col = lane&15, row = (lane>>4)*4 + reg
    int q4 = (lane >> 4) * 4;
    #pragma unroll
    for (int i = 0; i < 4; i++) {
        #pragma unroll
        for (int rr = 0; rr < 4; rr++) {
            int rg = bm + wr + i * 16 + q4 + rr;
            if (rg < M) {
                #pragma unroll
                for (int j = 0; j < 4; j++) {
                    int cg = bn + wc + j * 16 + mrow;
                    if (cg < N) {
                        float bv = (mode == 3 && cg >= nsplit) ? bias2[cg - nsplit]
                                                               : bias[cg];
                        float v = acc[i][j][rr] + bv;
                        size_t idx = (size_t)rg * N + cg;
                        if (mode == 0)      ((bf16*)C)[idx]  = __float2bfloat16(v);
                        else if (mode == 2) ((float*)C)[idx] = resid[idx] + gamma[cg] * v;
                        else                ((float*)C)[idx] = v;
                    }
                }
            }
        }
    }
}

// ---------------------------------------------------------------------------
// Deformable sampling, corner-parallel:
// one wave per (b,q,h) unit; lane = corner-slot (lane>>3) x channel-octet (lane&7).
// comb (B*LQ, 432) f32: cols 0..287 = offsets, 288..431 = logits.
// ---------------------------------------------------------------------------
__global__ __launch_bounds__(256) void sample_kernel(
    const bf16*  __restrict__ value,
    const float* __restrict__ comb,
    bf16*        __restrict__ attn)
{
    int unit = __builtin_amdgcn_readfirstlane((blockIdx.x << 2) + (threadIdx.x >> 6));
    int lane = threadIdx.x & 63;
    int o   = lane & 7;          // channel octet -> channels o*8..o*8+7
    int c8  = lane >> 3;         // corner slot 0..7
    int k   = c8 & 3;
    int dx  = k & 1, dy = k >> 1;
    int h  = unit % NH;
    int bq = unit / NH;
    int q  = bq & (LQ - 1);
    int b  = bq >> 12;

    const float* rowp = comb + (size_t)bq * 432;
    const float* ob = rowp + h * 24;
    const float* lg = rowp + 288 + h * 12;

    float l[12];
    float mx = -1e30f;
    #pragma unroll
    for (int i = 0; i < 12; i++) { l[i] = lg[i]; mx = fmaxf(mx, l[i]); }
    float den = 0.f;
    #pragma unroll
    for (int i = 0; i < 12; i++) { l[i] = __expf(l[i] - mx); den += l[i]; }
    float rden = 1.f / den;
    #pragma unroll
    for (int i = 0; i < 12; i++) l[i] *= rden;

    float rx = ((q & 63) + 0.5f) * (1.f / 64.f);
    float ry = ((q >> 6) + 0.5f) * (1.f / 64.f);

    float acc[8] = {0.f};

    #pragma unroll
    for (int it = 0; it < 6; it++) {
        const int wl = (it < 2) ? 112 : (it < 4 ? 56 : 28);
        const int sl = (it < 2) ? 0   : (it < 4 ? 12544 : 15680);
        int s = it * 2 + ((lane >> 5) & 1);
        float ox = ob[s * 2 + 0];
        float oy = ob[s * 2 + 1];
        float x = rx * wl + ox - 0.5f;
        float y = ry * wl + oy - 0.5f;
        float xf = floorf(x), yf = floorf(y);
        float wx = x - xf,  wy = y - yf;
        int xi = (int)xf + dx;
        int yi = (int)yf + dy;
        bool valid = ((unsigned)xi < (unsigned)wl) & ((unsigned)yi < (unsigned)wl);
        int xc = min(max(xi, 0), wl - 1);
        int yc = min(max(yi, 0), wl - 1);
        int cell = b * LIN + sl + yc * wl + xc;
        const uint4* vp = (const uint4*)(value + ((size_t)cell * NH + h) * HD + o * 8);
        uint4 v = *vp;
        float aw = (lane & 32) ? l[it * 2 + 1] : l[it * 2];
        float bw = (dx ? wx : 1.f - wx) * (dy ? wy : 1.f - wy);
        float w = valid ? aw * bw : 0.f;
        const unsigned* u = (const unsigned*)&v;
        #pragma unroll
        for (int j = 0; j < 4; j++) {
            float f0 = __uint_as_float(u[j] << 16);
            float f1 = __uint_as_float(u[j] & 0xFFFF0000u);
            acc[j * 2 + 0] = fmaf(w, f0, acc[j * 2 + 0]);
            acc[j * 2 + 1] = fmaf(w, f1, acc[j * 2 + 1]);
        }
    }

    #pragma unroll
    for (int m = 8; m <= 32; m <<= 1) {
        #pragma unroll
        for (int j = 0; j < 8; j++)
            acc[j] += __shfl_xor(acc[j], m);
    }

    if (c8 == 0) {
        union { bf16 h8[8]; uint4 u4; } r;
        #pragma unroll
        for (int j = 0; j < 8; j++) r.h8[j] = __float2bfloat16(acc[j]);
        *(uint4*)(attn + (size_t)bq * DM + h * HD + o * 8) = r.u4;
    }
}

// ---------------------------------------------------------------------------
extern "C" void kernel_launch(void* const* d_in, const int* in_sizes, int n_in,
                              void* d_out, int out_size, void* d_ws, size_t ws_size,
                              hipStream_t stream)
{
    const float* query  = (const float*)d_in[0];
    const float* feat   = (const float*)d_in[1];
    const float* ln_q_g = (const float*)d_in[2];
    const float* ln_q_b = (const float*)d_in[3];
    const float* ln_f_g = (const float*)d_in[4];
    const float* ln_f_b = (const float*)d_in[5];
    const float* W_off  = (const float*)d_in[6];
    const float* b_off  = (const float*)d_in[7];
    const float* W_attn = (const float*)d_in[8];
    const float* b_attn = (const float*)d_in[9];
    const float* W_val  = (const float*)d_in[10];
    const float* b_val  = (const float*)d_in[11];
    const float* W_out  = (const float*)d_in[12];
    const float* b_out  = (const float*)d_in[13];
    const float* gamma  = (const float*)d_in[14];
    float* out = (float*)d_out;

    char* ws = (char*)d_ws;
    char* od = (char*)d_out;
    const int M_F = BB * LIN;   // 65856
    const int M_Q = BB * LQ;    // 16384

    // ws layout (227,475,456 B proven):
    bf16*  value  = (bf16*)(ws);
    bf16*  f_ln   = (bf16*)(ws + 101154816);
    bf16*  Wt_out = (bf16*)(ws + 101154816);
    bf16*  q_ln   = (bf16*)(ws + 202309632);
    bf16*  attn   = (bf16*)(ws + 202309632);

    // d_out as scratch (dead before final GEMM):
    bf16*  Wt_val  = (bf16*)(od);
    bf16*  Wt_comb = (bf16*)(od + 1179648);
    float* comb    = (float*)(od + 2162688);

    // 1. weight cast/transpose
    cast_transpose<<<dim3(24, 24), 256, 0, stream>>>(W_val, Wt_val, 768);
    cast_transpose<<<dim3(9, 24), 256, 0, stream>>>(W_off, Wt_comb, 288);
    cast_transpose<<<dim3(7, 24), 256, 0, stream>>>(
        W_attn, Wt_comb + (size_t)288 * K_DIM, 144);

    // 2. LayerNorms (wave-per-row; rows are multiples of 4)
    ln_kernel<<<M_F / 4, 256, 0, stream>>>(feat, ln_f_g, ln_f_b, f_ln);
    ln_kernel<<<M_Q / 4, 256, 0, stream>>>(query, ln_q_g, ln_q_b, q_ln);

    // 3. value = f_ln @ W_val + b_val (bf16)
    mfma_gemm<<<dim3(6, (M_F + 127) / 128), 256, 0, stream>>>(
        f_ln, Wt_val, b_val, value, nullptr, nullptr, nullptr, M_F, DM, 0, 0);

    // 4. Wt_out into f_ln's (now dead) region
    cast_transpose<<<dim3(24, 24), 256, 0, stream>>>(W_out, Wt_out, 768);

    // 5. comb = q_ln @ [W_off | W_attn] + [b_off | b_attn] (f32, N=432)
    mfma_gemm<<<dim3(4, M_Q / 128), 256, 0, stream>>>(
        q_ln, Wt_comb, b_off, comb, nullptr, nullptr, b_attn, M_Q, 432, 3, 288);

    // 6. deformable sampling -> attn (bf16)
    sample_kernel<<<(M_Q * NH) / 4, 256, 0, stream>>>(value, comb, attn);

    // 7. out = query + gamma * (attn @ W_out + b_out)
    mfma_gemm<<<dim3(6, M_Q / 128), 256, 0, stream>>>(
        attn, Wt_out, b_out, out, query, gamma, nullptr, M_Q, DM, 2, 0);
}

// Round 2
// 797.530 us; speedup vs baseline: 1.0604x; 1.0604x over previous
//
#include <hip/hip_runtime.h>
#include <hip/hip_bf16.h>

typedef __hip_bfloat16 bf16;

// Problem constants
#define BB    4
#define LQ    4096
#define LIN   16464
#define DM    768
#define NH    12
#define HD    64
#define K_DIM 768
// Levels: (112,112),(56,56),(28,28); starts 0,12544,15680; query grid 64x64

typedef __attribute__((ext_vector_type(8))) __bf16 bfrag;
typedef __attribute__((ext_vector_type(4))) float  ffrag;

// ---------------------------------------------------------------------------
// async global->LDS 16B per lane (LDS dest is wave-uniform base + lane*16)
// ---------------------------------------------------------------------------
__device__ __forceinline__ void g2l16(const void* g, void* l) {
    __builtin_amdgcn_global_load_lds(
        (const __attribute__((address_space(1))) void*)g,
        (__attribute__((address_space(3))) void*)l, 16, 0, 0);
}

// bijective XCD-chunk swizzle (m204): dispatch i lands on XCD i%8; give each
// XCD a contiguous run of logical ids so neighbor work shares its private L2.
__device__ __forceinline__ int xcd_swz(int orig, int nwg) {
    int xcd = orig & 7, within = orig >> 3;
    int q = nwg >> 3, r = nwg & 7;
    return (xcd < r ? xcd * (q + 1) : r * (q + 1) + (xcd - r) * q) + within;
}

// ---------------------------------------------------------------------------
// LayerNorm over last dim 768: one wave per row, 4 rows/block.
// Pure shfl_xor reduction — no LDS, no barrier.
// ---------------------------------------------------------------------------
__global__ __launch_bounds__(256) void ln_kernel(
    const float* __restrict__ x, const float* __restrict__ g,
    const float* __restrict__ beta, bf16* __restrict__ y)
{
    int r = blockIdx.x * 4 + (threadIdx.x >> 6);
    int lane = threadIdx.x & 63;
    const float4* xr = (const float4*)(x + (size_t)r * DM);
    float4 v[3];
    #pragma unroll
    for (int i = 0; i < 3; i++) v[i] = xr[lane + 64 * i];
    float s = 0.f, ss = 0.f;
    #pragma unroll
    for (int i = 0; i < 3; i++) {
        s  += v[i].x + v[i].y + v[i].z + v[i].w;
        ss += v[i].x * v[i].x + v[i].y * v[i].y + v[i].z * v[i].z + v[i].w * v[i].w;
    }
    #pragma unroll
    for (int m = 1; m <= 32; m <<= 1) {
        s  += __shfl_xor(s, m);
        ss += __shfl_xor(ss, m);
    }
    float mean = s * (1.f / DM);
    float inv  = rsqrtf(ss * (1.f / DM) - mean * mean + 1e-6f);
    bf16* yr = y + (size_t)r * DM;
    #pragma unroll
    for (int i = 0; i < 3; i++) {
        float4 gg = ((const float4*)g)[lane + 64 * i];
        float4 bb = ((const float4*)beta)[lane + 64 * i];
        union { bf16 h[4]; uint2 u; } p;
        p.h[0] = __float2bfloat16((v[i].x - mean) * inv * gg.x + bb.x);
        p.h[1] = __float2bfloat16((v[i].y - mean) * inv * gg.y + bb.y);
        p.h[2] = __float2bfloat16((v[i].z - mean) * inv * gg.z + bb.z);
        p.h[3] = __float2bfloat16((v[i].w - mean) * inv * gg.w + bb.w);
        *(uint2*)(yr + (lane + 64 * i) * 4) = p.u;
    }
}

// ---------------------------------------------------------------------------
// Cast + transpose weights: W (768 x N f32, row-major) -> Wt (gridX*32 x 768 bf16)
// rows n >= N zero-filled. Grid: (rows/32, 768/32), block 256.
// ---------------------------------------------------------------------------
__global__ __launch_bounds__(256) void cast_transpose(
    const float* __restrict__ W, bf16* __restrict__ Wt, int N)
{
    __shared__ float t[32][33];
    int n0 = blockIdx.x * 32, k0 = blockIdx.y * 32;
    int tx = threadIdx.x & 31, ty = threadIdx.x >> 5;  // ty 0..7
    #pragma unroll
    for (int i = 0; i < 4; i++) {
        int k = k0 + ty + i * 8;
        int n = n0 + tx;
        t[ty + i * 8][tx] = (n < N) ? W[(size_t)k * N + n] : 0.f;
    }
    __syncthreads();
    #pragma unroll
    for (int i = 0; i < 4; i++) {
        int n = n0 + ty + i * 8;
        Wt[(size_t)n * K_DIM + k0 + tx] = __float2bfloat16(t[tx][ty + i * 8]);
    }
}

// ---------------------------------------------------------------------------
// MFMA bf16 GEMM: C(M,N) = A(M,768) @ Wt(N,768)^T + bias
// 128x128 tile, 256 threads (4 waves, 2x2 of 64x64), K-step 64 as two
// independent BK=32 sub-tiles: 8 staging loads + 32 MFMA per wave per
// barrier pair. Single 32KB buffer (R1's 64KB dbuf cost occupancy, zero gain).
// XCD-bijective block swizzle for A-panel L2 reuse (R1: FETCH 313->67MB).
// mode 0: bf16 store; mode 2: f32 = resid + gamma*(acc+bias);
// mode 3: f32 store, dual bias split at nsplit; else f32 store.
// ---------------------------------------------------------------------------
__global__ __launch_bounds__(256) void mfma_gemm(
    const bf16*  __restrict__ A,
    const bf16*  __restrict__ Bt,
    const float* __restrict__ bias,
    void*        __restrict__ C,
    const float* __restrict__ resid,
    const float* __restrict__ gamma,
    const float* __restrict__ bias2,
    int M, int N, int mode, int nsplit)
{
    __shared__ __align__(16) char lds[32768];   // 2 sub-tiles x (A 8K + B 8K)

    int tid  = threadIdx.x;
    int lane = tid & 63;

    int nwg  = gridDim.x * gridDim.y;
    int orig = blockIdx.y * gridDim.x + blockIdx.x;
    int wg = xcd_swz(orig, nwg);
    int bn = (wg % gridDim.x) * 128;
    int bm = (wg / gridDim.x) * 128;

    int wave = tid >> 6;
    int wr = (wave & 1) * 64, wc = (wave >> 1) * 64;

    ffrag acc[4][4] = {};

    // staging (per sub-tile): 512 chunks of 16B; thread covers chunks
    // tid, tid+256. chunk c: row = c>>2, K-octet = (c&3)*8.
    int c0 = tid, c1 = tid + 256;
    int r0 = c0 >> 2, kb0 = (c0 & 3) * 8;
    int r1 = c1 >> 2, kb1 = (c1 & 3) * 8;
    int ra0 = min(bm + r0, M - 1), ra1 = min(bm + r1, M - 1);
    const bf16* gA0 = A  + (size_t)ra0 * K_DIM + kb0;
    const bf16* gA1 = A  + (size_t)ra1 * K_DIM + kb1;
    const bf16* gB0 = Bt + (size_t)(bn + r0) * K_DIM + kb0;
    const bf16* gB1 = Bt + (size_t)(bn + r1) * K_DIM + kb1;

    int mrow = lane & 15;
    int kq   = (lane >> 4) * 8;

    for (int k0 = 0; k0 < K_DIM; k0 += 64) {
        #pragma unroll
        for (int s = 0; s < 2; s++) {
            char* As = lds + s * 16384;
            char* Bs = As + 8192;
            int ko = k0 + s * 32;
            g2l16(gA0 + ko, As + c0 * 16);
            g2l16(gA1 + ko, As + c1 * 16);
            g2l16(gB0 + ko, Bs + c0 * 16);
            g2l16(gB1 + ko, Bs + c1 * 16);
        }
        __syncthreads();
        #pragma unroll
        for (int s = 0; s < 2; s++) {
            char* As = lds + s * 16384;
            char* Bs = As + 8192;
            bfrag a[4], b[4];
            #pragma unroll
            for (int t = 0; t < 4; t++) {
                a[t] = *(const bfrag*)(As + ((wr + t * 16 + mrow) * 32 + kq) * 2);
                b[t] = *(const bfrag*)(Bs + ((wc + t * 16 + mrow) * 32 + kq) * 2);
            }
            #pragma unroll
            for (int i = 0; i < 4; i++)
                #pragma unroll
                for (int j = 0; j < 4; j++)
                    acc[i][j] = __builtin_amdgcn_mfma_f32_16x16x32_bf16(
                        a[i], b[j], acc[i][j], 0, 0, 0);
        }
        __syncthreads();
    }

    // epilogue: C/D layout col = lane&15, row = (lane>>4)*4 + reg
    int q4 = (lane >> 4) * 4;
    #pragma unroll
    for (int i = 0; i < 4; i++) {
        #pragma unroll
        for (int rr = 0; rr < 4; rr++) {
            int rg = bm + wr + i * 16 + q4 + rr;
            if (rg < M) {
                #pragma unroll
                for (int j = 0; j < 4; j++) {
                    int cg = bn + wc + j * 16 + mrow;
                    if (cg < N) {
                        float bv = (mode == 3 && cg >= nsplit) ? bias2[cg - nsplit]
                                                               : bias[cg];
                        float v = acc[i][j][rr] + bv;
                        size_t idx = (size_t)rg * N + cg;
                        if (mode == 0)      ((bf16*)C)[idx]  = __float2bfloat16(v);
                        else if (mode == 2) ((float*)C)[idx] = resid[idx] + gamma[cg] * v;
                        else                ((float*)C)[idx] = v;
                    }
                }
            }
        }
    }
}

// ---------------------------------------------------------------------------
// Deformable sampling, corner-parallel:
// one wave per (b,q,h) unit; lane = corner-slot (lane>>3) x channel-octet (lane&7).
// comb (B*LQ, 432) f32: cols 0..287 = offsets, 288..431 = logits.
// XCD-chunked block swizzle: consecutive bq (raster-ordered queries) sample
// overlapping `value` regions (~1MB sliding window); chunking keeps that
// window in ONE per-XCD L2 instead of shattering it across 8.
// ---------------------------------------------------------------------------
__global__ __launch_bounds__(256) void sample_kernel(
    const bf16*  __restrict__ value,
    const float* __restrict__ comb,
    bf16*        __restrict__ attn)
{
    int wg = xcd_swz(blockIdx.x, gridDim.x);
    int unit = __builtin_amdgcn_readfirstlane((wg << 2) + (threadIdx.x >> 6));
    int lane = threadIdx.x & 63;
    int o   = lane & 7;          // channel octet -> channels o*8..o*8+7
    int c8  = lane >> 3;         // corner slot 0..7
    int k   = c8 & 3;
    int dx  = k & 1, dy = k >> 1;
    int h  = unit % NH;
    int bq = unit / NH;
    int q  = bq & (LQ - 1);
    int b  = bq >> 12;

    const float* rowp = comb + (size_t)bq * 432;
    const float* ob = rowp + h * 24;
    const float* lg = rowp + 288 + h * 12;

    float l[12];
    float mx = -1e30f;
    #pragma unroll
    for (int i = 0; i < 12; i++) { l[i] = lg[i]; mx = fmaxf(mx, l[i]); }
    float den = 0.f;
    #pragma unroll
    for (int i = 0; i < 12; i++) { l[i] = __expf(l[i] - mx); den += l[i]; }
    float rden = 1.f / den;
    #pragma unroll
    for (int i = 0; i < 12; i++) l[i] *= rden;

    float rx = ((q & 63) + 0.5f) * (1.f / 64.f);
    float ry = ((q >> 6) + 0.5f) * (1.f / 64.f);

    float acc[8] = {0.f};

    #pragma unroll
    for (int it = 0; it < 6; it++) {
        const int wl = (it < 2) ? 112 : (it < 4 ? 56 : 28);
        const int sl = (it < 2) ? 0   : (it < 4 ? 12544 : 15680);
        int s = it * 2 + ((lane >> 5) & 1);
        float ox = ob[s * 2 + 0];
        float oy = ob[s * 2 + 1];
        float x = rx * wl + ox - 0.5f;
        float y = ry * wl + oy - 0.5f;
        float xf = floorf(x), yf = floorf(y);
        float wx = x - xf,  wy = y - yf;
        int xi = (int)xf + dx;
        int yi = (int)yf + dy;
        bool valid = ((unsigned)xi < (unsigned)wl) & ((unsigned)yi < (unsigned)wl);
        int xc = min(max(xi, 0), wl - 1);
        int yc = min(max(yi, 0), wl - 1);
        int cell = b * LIN + sl + yc * wl + xc;
        const uint4* vp = (const uint4*)(value + ((size_t)cell * NH + h) * HD + o * 8);
        uint4 v = *vp;
        float aw = (lane & 32) ? l[it * 2 + 1] : l[it * 2];
        float bw = (dx ? wx : 1.f - wx) * (dy ? wy : 1.f - wy);
        float w = valid ? aw * bw : 0.f;
        const unsigned* u = (const unsigned*)&v;
        #pragma unroll
        for (int j = 0; j < 4; j++) {
            float f0 = __uint_as_float(u[j] << 16);
            float f1 = __uint_as_float(u[j] & 0xFFFF0000u);
            acc[j * 2 + 0] = fmaf(w, f0, acc[j * 2 + 0]);
            acc[j * 2 + 1] = fmaf(w, f1, acc[j * 2 + 1]);
        }
    }

    #pragma unroll
    for (int m = 8; m <= 32; m <<= 1) {
        #pragma unroll
        for (int j = 0; j < 8; j++)
            acc[j] += __shfl_xor(acc[j], m);
    }

    if (c8 == 0) {
        union { bf16 h8[8]; uint4 u4; } r;
        #pragma unroll
        for (int j = 0; j < 8; j++) r.h8[j] = __float2bfloat16(acc[j]);
        *(uint4*)(attn + (size_t)bq * DM + h * HD + o * 8) = r.u4;
    }
}

// ---------------------------------------------------------------------------
extern "C" void kernel_launch(void* const* d_in, const int* in_sizes, int n_in,
                              void* d_out, int out_size, void* d_ws, size_t ws_size,
                              hipStream_t stream)
{
    const float* query  = (const float*)d_in[0];
    const float* feat   = (const float*)d_in[1];
    const float* ln_q_g = (const float*)d_in[2];
    const float* ln_q_b = (const float*)d_in[3];
    const float* ln_f_g = (const float*)d_in[4];
    const float* ln_f_b = (const float*)d_in[5];
    const float* W_off  = (const float*)d_in[6];
    const float* b_off  = (const float*)d_in[7];
    const float* W_attn = (const float*)d_in[8];
    const float* b_attn = (const float*)d_in[9];
    const float* W_val  = (const float*)d_in[10];
    const float* b_val  = (const float*)d_in[11];
    const float* W_out  = (const float*)d_in[12];
    const float* b_out  = (const float*)d_in[13];
    const float* gamma  = (const float*)d_in[14];
    float* out = (float*)d_out;

    char* ws = (char*)d_ws;
    char* od = (char*)d_out;
    const int M_F = BB * LIN;   // 65856
    const int M_Q = BB * LQ;    // 16384

    // ws layout (227,475,456 B proven):
    bf16*  value  = (bf16*)(ws);
    bf16*  f_ln   = (bf16*)(ws + 101154816);
    bf16*  Wt_out = (bf16*)(ws + 101154816);
    bf16*  q_ln   = (bf16*)(ws + 202309632);
    bf16*  attn   = (bf16*)(ws + 202309632);

    // d_out as scratch (dead before final GEMM):
    bf16*  Wt_val  = (bf16*)(od);
    bf16*  Wt_comb = (bf16*)(od + 1179648);
    float* comb    = (float*)(od + 2162688);

    // 1. weight cast/transpose
    cast_transpose<<<dim3(24, 24), 256, 0, stream>>>(W_val, Wt_val, 768);
    cast_transpose<<<dim3(9, 24), 256, 0, stream>>>(W_off, Wt_comb, 288);
    cast_transpose<<<dim3(7, 24), 256, 0, stream>>>(
        W_attn, Wt_comb + (size_t)288 * K_DIM, 144);

    // 2. LayerNorms (wave-per-row; rows are multiples of 4)
    ln_kernel<<<M_F / 4, 256, 0, stream>>>(feat, ln_f_g, ln_f_b, f_ln);
    ln_kernel<<<M_Q / 4, 256, 0, stream>>>(query, ln_q_g, ln_q_b, q_ln);

    // 3. value = f_ln @ W_val + b_val (bf16)
    mfma_gemm<<<dim3(6, (M_F + 127) / 128), 256, 0, stream>>>(
        f_ln, Wt_val, b_val, value, nullptr, nullptr, nullptr, M_F, DM, 0, 0);

    // 4. Wt_out into f_ln's (now dead) region
    cast_transpose<<<dim3(24, 24), 256, 0, stream>>>(W_out, Wt_out, 768);

    // 5. comb = q_ln @ [W_off | W_attn] + [b_off | b_attn] (f32, N=432)
    mfma_gemm<<<dim3(4, M_Q / 128), 256, 0, stream>>>(
        q_ln, Wt_comb, b_off, comb, nullptr, nullptr, b_attn, M_Q, 432, 3, 288);

    // 6. deformable sampling -> attn (bf16)
    sample_kernel<<<(M_Q * NH) / 4, 256, 0, stream>>>(value, comb, attn);

    // 7. out = query + gamma * (attn @ W_out + b_out)
    mfma_gemm<<<dim3(6, M_Q / 128), 256, 0, stream>>>(
        attn, Wt_out, b_out, out, query, gamma, nullptr, M_Q, DM, 2, 0);
}

// Round 3
// 776.548 us; speedup vs baseline: 1.0890x; 1.0270x over previous
//
#include <hip/hip_runtime.h>
#include <hip/hip_bf16.h>

typedef __hip_bfloat16 bf16;

// Problem constants
#define BB    4
#define LQ    4096
#define LIN   16464
#define DM    768
#define NH    12
#define HD    64
#define K_DIM 768
// Levels: (112,112),(56,56),(28,28); starts 0,12544,15680; query grid 64x64

typedef __attribute__((ext_vector_type(8))) __bf16 bfrag;
typedef __attribute__((ext_vector_type(4))) float  ffrag;

// ---------------------------------------------------------------------------
// async global->LDS 16B per lane (LDS dest is wave-uniform base + lane*16)
// ---------------------------------------------------------------------------
__device__ __forceinline__ void g2l16(const void* g, void* l) {
    __builtin_amdgcn_global_load_lds(
        (const __attribute__((address_space(1))) void*)g,
        (__attribute__((address_space(3))) void*)l, 16, 0, 0);
}

// bijective XCD-chunk swizzle (m204): dispatch i lands on XCD i%8; give each
// XCD a contiguous run of logical ids so neighbor work shares its private L2.
__device__ __forceinline__ int xcd_swz(int orig, int nwg) {
    int xcd = orig & 7, within = orig >> 3;
    int q = nwg >> 3, r = nwg & 7;
    return (xcd < r ? xcd * (q + 1) : r * (q + 1) + (xcd - r) * q) + within;
}

// ---------------------------------------------------------------------------
// LayerNorm over last dim 768: one wave per row, 4 rows/block.
// Pure shfl_xor reduction — no LDS, no barrier.
// ---------------------------------------------------------------------------
__global__ __launch_bounds__(256) void ln_kernel(
    const float* __restrict__ x, const float* __restrict__ g,
    const float* __restrict__ beta, bf16* __restrict__ y)
{
    int r = blockIdx.x * 4 + (threadIdx.x >> 6);
    int lane = threadIdx.x & 63;
    const float4* xr = (const float4*)(x + (size_t)r * DM);
    float4 v[3];
    #pragma unroll
    for (int i = 0; i < 3; i++) v[i] = xr[lane + 64 * i];
    float s = 0.f, ss = 0.f;
    #pragma unroll
    for (int i = 0; i < 3; i++) {
        s  += v[i].x + v[i].y + v[i].z + v[i].w;
        ss += v[i].x * v[i].x + v[i].y * v[i].y + v[i].z * v[i].z + v[i].w * v[i].w;
    }
    #pragma unroll
    for (int m = 1; m <= 32; m <<= 1) {
        s  += __shfl_xor(s, m);
        ss += __shfl_xor(ss, m);
    }
    float mean = s * (1.f / DM);
    float inv  = rsqrtf(ss * (1.f / DM) - mean * mean + 1e-6f);
    bf16* yr = y + (size_t)r * DM;
    #pragma unroll
    for (int i = 0; i < 3; i++) {
        float4 gg = ((const float4*)g)[lane + 64 * i];
        float4 bb = ((const float4*)beta)[lane + 64 * i];
        union { bf16 h[4]; uint2 u; } p;
        p.h[0] = __float2bfloat16((v[i].x - mean) * inv * gg.x + bb.x);
        p.h[1] = __float2bfloat16((v[i].y - mean) * inv * gg.y + bb.y);
        p.h[2] = __float2bfloat16((v[i].z - mean) * inv * gg.z + bb.z);
        p.h[3] = __float2bfloat16((v[i].w - mean) * inv * gg.w + bb.w);
        *(uint2*)(yr + (lane + 64 * i) * 4) = p.u;
    }
}

// ---------------------------------------------------------------------------
// Cast + transpose weights: W (768 x N f32, row-major) -> Wt (gridX*32 x 768 bf16)
// rows n >= N zero-filled. Grid: (rows/32, 768/32), block 256.
// ---------------------------------------------------------------------------
__global__ __launch_bounds__(256) void cast_transpose(
    const float* __restrict__ W, bf16* __restrict__ Wt, int N)
{
    __shared__ float t[32][33];
    int n0 = blockIdx.x * 32, k0 = blockIdx.y * 32;
    int tx = threadIdx.x & 31, ty = threadIdx.x >> 5;  // ty 0..7
    #pragma unroll
    for (int i = 0; i < 4; i++) {
        int k = k0 + ty + i * 8;
        int n = n0 + tx;
        t[ty + i * 8][tx] = (n < N) ? W[(size_t)k * N + n] : 0.f;
    }
    __syncthreads();
    #pragma unroll
    for (int i = 0; i < 4; i++) {
        int n = n0 + ty + i * 8;
        Wt[(size_t)n * K_DIM + k0 + tx] = __float2bfloat16(t[tx][ty + i * 8]);
    }
}

// ---------------------------------------------------------------------------
// MFMA bf16 GEMM: C(M,N) = A(M,768) @ Wt(N,768)^T + bias
// 128x128 tile, 256 threads (4 waves, 2x2 of 64x64).
// K-step 32, 3-deep LDS rotation (3 x 16KB), COUNTED vmcnt(8) — tiles kt+1
// and kt+2 stay in flight across barriers (never drain to 0 in-loop).
// Raw s_barrier (no compiler vmcnt(0) drain); 2nd barrier needs no drain:
// each wave's ds_reads are consumed by its MFMAs before it arrives.
// LDS slot-swizzle slot^=(row>>1)&3, pre-applied on the global source
// (rule 21) and in the read address: 8-way bank conflict -> 2-way (free).
// XCD-bijective block swizzle for A-panel L2 reuse (FETCH 313->67MB).
// mode 0: bf16 store; mode 2: f32 = resid + gamma*(acc+bias);
// mode 3: f32 store, dual bias split at nsplit; else f32 store.
// ---------------------------------------------------------------------------
__global__ __launch_bounds__(256) void mfma_gemm(
    const bf16*  __restrict__ A,
    const bf16*  __restrict__ Bt,
    const float* __restrict__ bias,
    void*        __restrict__ C,
    const float* __restrict__ resid,
    const float* __restrict__ gamma,
    const float* __restrict__ bias2,
    int M, int N, int mode, int nsplit)
{
    __shared__ __align__(16) char lds[49152];   // 3 buffers x (A 8K + B 8K)

    int tid  = threadIdx.x;
    int lane = tid & 63;

    int nwg  = gridDim.x * gridDim.y;
    int orig = blockIdx.y * gridDim.x + blockIdx.x;
    int wg = xcd_swz(orig, nwg);
    int bn = (wg % gridDim.x) * 128;
    int bm = (wg / gridDim.x) * 128;

    int wave = tid >> 6;
    int wr = (wave & 1) * 64, wc = (wave >> 1) * 64;

    ffrag acc[4][4] = {};

    // staging: per 16KB buffer, A sub-tile 8KB [128 rows][32 k] + B 8KB.
    // 512 chunks of 16B per sub-tile; thread covers chunks tid, tid+256.
    // chunk c: row r = c>>2, slot = c&3. Swizzle: LDS slot s holds global
    // k-octet s ^ ((r>>1)&3)  (involution; same for r and r+64).
    int rA = tid >> 2;                       // 0..63
    int kb = (((tid & 3) ^ ((rA >> 1) & 3)) * 8);
    int ra0 = min(bm + rA, M - 1), ra1 = min(bm + 64 + rA, M - 1);
    const bf16* gA0 = A  + (size_t)ra0 * K_DIM + kb;
    const bf16* gA1 = A  + (size_t)ra1 * K_DIM + kb;
    const bf16* gB0 = Bt + (size_t)(bn + rA) * K_DIM + kb;
    const bf16* gB1 = Bt + (size_t)(bn + 64 + rA) * K_DIM + kb;

    int mrow = lane & 15;
    // read-side swizzled k-octet: slot = (lane>>4) ^ ((row>>1)&3); row&15=mrow
    int kqs  = (((lane >> 4) ^ ((mrow >> 1) & 3)) * 8);

    auto stage = [&](char* buf, int kt) {
        const int ko = kt * 32;
        g2l16(gA0 + ko, buf + tid * 16);
        g2l16(gA1 + ko, buf + tid * 16 + 4096);
        g2l16(gB0 + ko, buf + 8192 + tid * 16);
        g2l16(gB1 + ko, buf + 8192 + tid * 16 + 4096);
    };

    char* b0 = lds;
    char* b1 = lds + 16384;
    char* b2 = lds + 32768;
    stage(b0, 0); stage(b1, 1); stage(b2, 2);   // 12 loads in flight

    #pragma unroll
    for (int kt = 0; kt < 24; kt++) {
        // wait only for tile kt's 4 loads; keep kt+1/kt+2 (8 loads) flying
        if (kt + 2 < 24)      asm volatile("s_waitcnt vmcnt(8)" ::: "memory");
        else if (kt + 1 < 24) asm volatile("s_waitcnt vmcnt(4)" ::: "memory");
        else                  asm volatile("s_waitcnt vmcnt(0)" ::: "memory");
        __builtin_amdgcn_s_barrier();
        __builtin_amdgcn_sched_barrier(0);

        bfrag a[4], b[4];
        #pragma unroll
        for (int t = 0; t < 4; t++) {
            a[t] = *(const bfrag*)(b0 + ((wr + t * 16 + mrow) * 32 + kqs) * 2);
            b[t] = *(const bfrag*)(b0 + 8192 + ((wc + t * 16 + mrow) * 32 + kqs) * 2);
        }
        #pragma unroll
        for (int i = 0; i < 4; i++)
            #pragma unroll
            for (int j = 0; j < 4; j++)
                acc[i][j] = __builtin_amdgcn_mfma_f32_16x16x32_bf16(
                    a[i], b[j], acc[i][j], 0, 0, 0);

        __builtin_amdgcn_sched_barrier(0);
        __builtin_amdgcn_s_barrier();       // all waves done reading b0
        __builtin_amdgcn_sched_barrier(0);
        if (kt + 3 < 24) stage(b0, kt + 3); // refill freed buffer
        char* tp = b0; b0 = b1; b1 = b2; b2 = tp;
    }

    // epilogue: C/D layout col = lane&15, row = (lane>>4)*4 + reg
    int q4 = (lane >> 4) * 4;
    #pragma unroll
    for (int i = 0; i < 4; i++) {
        #pragma unroll
        for (int rr = 0; rr < 4; rr++) {
            int rg = bm + wr + i * 16 + q4 + rr;
            if (rg < M) {
                #pragma unroll
                for (int j = 0; j < 4; j++) {
                    int cg = bn + wc + j * 16 + mrow;
                    if (cg < N) {
                        float bv = (mode == 3 && cg >= nsplit) ? bias2[cg - nsplit]
                                                               : bias[cg];
                        float v = acc[i][j][rr] + bv;
                        size_t idx = (size_t)rg * N + cg;
                        if (mode == 0)      ((bf16*)C)[idx]  = __float2bfloat16(v);
                        else if (mode == 2) ((float*)C)[idx] = resid[idx] + gamma[cg] * v;
                        else                ((float*)C)[idx] = v;
                    }
                }
            }
        }
    }
}

// ---------------------------------------------------------------------------
// Deformable sampling, corner-parallel:
// one wave per (b,q,h) unit; lane = corner-slot (lane>>3) x channel-octet (lane&7).
// comb (B*LQ, 432) f32: cols 0..287 = offsets, 288..431 = logits.
// ---------------------------------------------------------------------------
__global__ __launch_bounds__(256) void sample_kernel(
    const bf16*  __restrict__ value,
    const float* __restrict__ comb,
    bf16*        __restrict__ attn)
{
    int wg = xcd_swz(blockIdx.x, gridDim.x);
    int unit = __builtin_amdgcn_readfirstlane((wg << 2) + (threadIdx.x >> 6));
    int lane = threadIdx.x & 63;
    int o   = lane & 7;          // channel octet -> channels o*8..o*8+7
    int c8  = lane >> 3;         // corner slot 0..7
    int k   = c8 & 3;
    int dx  = k & 1, dy = k >> 1;
    int h  = unit % NH;
    int bq = unit / NH;
    int q  = bq & (LQ - 1);
    int b  = bq >> 12;

    const float* rowp = comb + (size_t)bq * 432;
    const float* ob = rowp + h * 24;
    const float* lg = rowp + 288 + h * 12;

    float l[12];
    float mx = -1e30f;
    #pragma unroll
    for (int i = 0; i < 12; i++) { l[i] = lg[i]; mx = fmaxf(mx, l[i]); }
    float den = 0.f;
    #pragma unroll
    for (int i = 0; i < 12; i++) { l[i] = __expf(l[i] - mx); den += l[i]; }
    float rden = 1.f / den;
    #pragma unroll
    for (int i = 0; i < 12; i++) l[i] *= rden;

    float rx = ((q & 63) + 0.5f) * (1.f / 64.f);
    float ry = ((q >> 6) + 0.5f) * (1.f / 64.f);

    float acc[8] = {0.f};

    #pragma unroll
    for (int it = 0; it < 6; it++) {
        const int wl = (it < 2) ? 112 : (it < 4 ? 56 : 28);
        const int sl = (it < 2) ? 0   : (it < 4 ? 12544 : 15680);
        int s = it * 2 + ((lane >> 5) & 1);
        float ox = ob[s * 2 + 0];
        float oy = ob[s * 2 + 1];
        float x = rx * wl + ox - 0.5f;
        float y = ry * wl + oy - 0.5f;
        float xf = floorf(x), yf = floorf(y);
        float wx = x - xf,  wy = y - yf;
        int xi = (int)xf + dx;
        int yi = (int)yf + dy;
        bool valid = ((unsigned)xi < (unsigned)wl) & ((unsigned)yi < (unsigned)wl);
        int xc = min(max(xi, 0), wl - 1);
        int yc = min(max(yi, 0), wl - 1);
        int cell = b * LIN + sl + yc * wl + xc;
        const uint4* vp = (const uint4*)(value + ((size_t)cell * NH + h) * HD + o * 8);
        uint4 v = *vp;
        float aw = (lane & 32) ? l[it * 2 + 1] : l[it * 2];
        float bw = (dx ? wx : 1.f - wx) * (dy ? wy : 1.f - wy);
        float w = valid ? aw * bw : 0.f;
        const unsigned* u = (const unsigned*)&v;
        #pragma unroll
        for (int j = 0; j < 4; j++) {
            float f0 = __uint_as_float(u[j] << 16);
            float f1 = __uint_as_float(u[j] & 0xFFFF0000u);
            acc[j * 2 + 0] = fmaf(w, f0, acc[j * 2 + 0]);
            acc[j * 2 + 1] = fmaf(w, f1, acc[j * 2 + 1]);
        }
    }

    #pragma unroll
    for (int m = 8; m <= 32; m <<= 1) {
        #pragma unroll
        for (int j = 0; j < 8; j++)
            acc[j] += __shfl_xor(acc[j], m);
    }

    if (c8 == 0) {
        union { bf16 h8[8]; uint4 u4; } r;
        #pragma unroll
        for (int j = 0; j < 8; j++) r.h8[j] = __float2bfloat16(acc[j]);
        *(uint4*)(attn + (size_t)bq * DM + h * HD + o * 8) = r.u4;
    }
}

// ---------------------------------------------------------------------------
extern "C" void kernel_launch(void* const* d_in, const int* in_sizes, int n_in,
                              void* d_out, int out_size, void* d_ws, size_t ws_size,
                              hipStream_t stream)
{
    const float* query  = (const float*)d_in[0];
    const float* feat   = (const float*)d_in[1];
    const float* ln_q_g = (const float*)d_in[2];
    const float* ln_q_b = (const float*)d_in[3];
    const float* ln_f_g = (const float*)d_in[4];
    const float* ln_f_b = (const float*)d_in[5];
    const float* W_off  = (const float*)d_in[6];
    const float* b_off  = (const float*)d_in[7];
    const float* W_attn = (const float*)d_in[8];
    const float* b_attn = (const float*)d_in[9];
    const float* W_val  = (const float*)d_in[10];
    const float* b_val  = (const float*)d_in[11];
    const float* W_out  = (const float*)d_in[12];
    const float* b_out  = (const float*)d_in[13];
    const float* gamma  = (const float*)d_in[14];
    float* out = (float*)d_out;

    char* ws = (char*)d_ws;
    char* od = (char*)d_out;
    const int M_F = BB * LIN;   // 65856
    const int M_Q = BB * LQ;    // 16384

    // ws layout (227,475,456 B proven):
    bf16*  value  = (bf16*)(ws);
    bf16*  f_ln   = (bf16*)(ws + 101154816);
    bf16*  Wt_out = (bf16*)(ws + 101154816);
    bf16*  q_ln   = (bf16*)(ws + 202309632);
    bf16*  attn   = (bf16*)(ws + 202309632);

    // d_out as scratch (dead before final GEMM):
    bf16*  Wt_val  = (bf16*)(od);
    bf16*  Wt_comb = (bf16*)(od + 1179648);
    float* comb    = (float*)(od + 2162688);

    // 1. weight cast/transpose
    cast_transpose<<<dim3(24, 24), 256, 0, stream>>>(W_val, Wt_val, 768);
    cast_transpose<<<dim3(9, 24), 256, 0, stream>>>(W_off, Wt_comb, 288);
    cast_transpose<<<dim3(7, 24), 256, 0, stream>>>(
        W_attn, Wt_comb + (size_t)288 * K_DIM, 144);

    // 2. LayerNorms (wave-per-row; rows are multiples of 4)
    ln_kernel<<<M_F / 4, 256, 0, stream>>>(feat, ln_f_g, ln_f_b, f_ln);
    ln_kernel<<<M_Q / 4, 256, 0, stream>>>(query, ln_q_g, ln_q_b, q_ln);

    // 3. value = f_ln @ W_val + b_val (bf16)
    mfma_gemm<<<dim3(6, (M_F + 127) / 128), 256, 0, stream>>>(
        f_ln, Wt_val, b_val, value, nullptr, nullptr, nullptr, M_F, DM, 0, 0);

    // 4. Wt_out into f_ln's (now dead) region
    cast_transpose<<<dim3(24, 24), 256, 0, stream>>>(W_out, Wt_out, 768);

    // 5. comb = q_ln @ [W_off | W_attn] + [b_off | b_attn] (f32, N=432)
    mfma_gemm<<<dim3(4, M_Q / 128), 256, 0, stream>>>(
        q_ln, Wt_comb, b_off, comb, nullptr, nullptr, b_attn, M_Q, 432, 3, 288);

    // 6. deformable sampling -> attn (bf16)
    sample_kernel<<<(M_Q * NH) / 4, 256, 0, stream>>>(value, comb, attn);

    // 7. out = query + gamma * (attn @ W_out + b_out)
    mfma_gemm<<<dim3(6, M_Q / 128), 256, 0, stream>>>(
        attn, Wt_out, b_out, out, query, gamma, nullptr, M_Q, DM, 2, 0);
}